// Round 4
// baseline (256.858 us; speedup 1.0000x reference)
//
#include <hip/hip_runtime.h>

// ROUND 4 = ROUND 3 RESUBMIT: round-3 bench died with "container failed twice"
// (broker infra, no kernel verdict).  Source re-audited for OOB/LDS/barrier
// hazards — none found.  Same candidate, same prediction (~203 us).

#define B_ 2
#define N_ 2048
#define F_ 64
#define C_ 64
#define L_ 4
#define SK 4    // split-K factor over j: 4 blocks/CU for latency decorrelation
#define NJ (N_ / SK)        // 512 j per block
#define TSTEPS (NJ / 32)    // 16 K-steps
#define PJ 40   // padded LDS j-stride (halves): 80 B rows -> 16B-aligned b128 reads, ~2-way banks

typedef _Float16 half8 __attribute__((ext_vector_type(8)));
typedef _Float16 half2 __attribute__((ext_vector_type(2)));
typedef float floatx4 __attribute__((ext_vector_type(4)));

// ---------------------------------------------------------------------------
// K0': fold the weights into the V-side BEFORE the big A pass.
//   U3[b][l][c][j] = sum_f V[b,j,f] * w3[l*64+f, c]   (fp16, 2 MB)  — B-operand for K1
//   U2[b][i][l][c] = sum_f V[b,i,f] * w2[l*64+f, c]   (fp32, 4 MB)  — deg-weighted term
//   T1[b][i][c]    = sum_f V[b,i,f] * w1[f, c]        (fp32, 1 MB)
// This makes K1's output directly [i,c] (term3), deleting the 16 MB aggT
// round-trip and K2's GEMM work entirely.
// grid = B * N/16 = 256 blocks (1/CU), 256 thr.  ~300 MFLOP fp32 VALU ≈ 2 us.
// ---------------------------------------------------------------------------
__global__ __launch_bounds__(256) void k0_embed(const float* __restrict__ V,
                                                const float* __restrict__ w1,
                                                const float* __restrict__ w2,
                                                const float* __restrict__ w3,
                                                _Float16* __restrict__ U3,
                                                float* __restrict__ U2,
                                                float* __restrict__ T1) {
    __shared__ float vt[16][64];
    const int b  = blockIdx.x >> 7;           // 0..1
    const int j0 = (blockIdx.x & 127) * 16;   // row-tile base (j for U3, i for U2/T1)
    const int tid = threadIdx.x;

    // stage 16 V rows (4 KB), one float4 per thread, coalesced
    {
        const floatx4* Vv = (const floatx4*)(V + ((size_t)(b * N_ + j0)) * F_);
        floatx4 v = Vv[tid];
        *(floatx4*)&vt[tid >> 4][(tid & 15) * 4] = v;
    }
    __syncthreads();

    const int l = tid >> 6;    // wave = edge type
    const int c = tid & 63;    // lane = output column (coalesced weight loads)

    float a3[16], a2[16];
#pragma unroll
    for (int r = 0; r < 16; ++r) { a3[r] = 0.0f; a2[r] = 0.0f; }
    float a1[4] = {0.0f, 0.0f, 0.0f, 0.0f};

#pragma unroll 4
    for (int f = 0; f < 64; ++f) {
        const float W3 = w3[(l * 64 + f) * 64 + c];   // 256 B coalesced per wave
        const float W2 = w2[(l * 64 + f) * 64 + c];
        const float W1 = w1[f * 64 + c];
#pragma unroll
        for (int r = 0; r < 16; ++r) {
            const float x = vt[r][f];                 // LDS broadcast
            a3[r] += x * W3;
            a2[r] += x * W2;
        }
#pragma unroll
        for (int r = 0; r < 4; ++r) a1[r] += vt[l * 4 + r][f] * W1;   // wave l -> rows 4l..4l+3
    }

    // U3[b][l][c][j] fp16 (RNE): 16 consecutive j halves per thread
    {
        _Float16* du = U3 + (((size_t)b * 4 + l) * 64 + c) * N_ + j0;
#pragma unroll
        for (int r = 0; r < 16; r += 2) {
            half2 h = {(_Float16)a3[r], (_Float16)a3[r + 1]};
            *(half2*)(du + r) = h;
        }
    }
    // U2[b][i][l][c] fp32: per row, 256 consecutive floats across the block
#pragma unroll
    for (int r = 0; r < 16; ++r)
        U2[(((size_t)(b * N_ + j0 + r)) * 4 + l) * 64 + c] = a2[r];
    // T1[b][i][c]
#pragma unroll
    for (int r = 0; r < 4; ++r)
        T1[((size_t)(b * N_ + j0 + l * 4 + r)) * 64 + c] = a1[r];
}

// ---------------------------------------------------------------------------
// K1: term3 partials DIRECTLY in [i,c] space.  Identical A staging / MFMA
// structure to the verified kernel (5 MFMA/wave/step incl. deg-ones), but the
// B-operand is now U3[j, l=w, c] instead of V[j, f].  Epilogue: cross-wave
// l-reduce via 16 KB LDS, then one 4 KB coalesced partial write per block
// (vs 16 KB aggT before).  grid = B * N/16 * SK = 1024 blocks (4/CU), 256 thr.
// ---------------------------------------------------------------------------
__global__ __launch_bounds__(256, 4) void k1_agg(const float* __restrict__ A,
                                                 const _Float16* __restrict__ U3,
                                                 float* __restrict__ Ppart,
                                                 float* __restrict__ degT) {
    __shared__ _Float16 lds[2 * 4 * 16 * PJ];   // 10 KB: [buf][l][i][PJ]
    __shared__ float red[4][16][64];            // 16 KB: per-wave l-partials

    const int bid = blockIdx.x;          // 0..1023
    const int b   = bid >> 9;
    const int rem = bid & 511;
    const int i0  = (rem >> 2) * 16;
    const int p   = rem & 3;             // split-K slice
    const int tid  = threadIdx.x;
    const int w    = tid >> 6;       // wave id == l
    const int lane = tid & 63;
    const int m    = lane & 15;      // B col (c within 16-tile) / C col
    const int q    = lane >> 4;      // quad group

    // staging mapping: thread -> (row i_s, j-pair jp)
    const int i_s = tid >> 4;        // 0..15
    const int jp  = tid & 15;        // 0..15 -> j = 2jp, 2jp+1

    const floatx4* Abase = (const floatx4*)A + ((size_t)(b * N_ + i0 + i_s)) * N_ + p * NJ;
    const _Float16* Urow = U3 + (((size_t)b * 4 + w) * 64) * N_ + p * NJ;   // wave w's l-plane

    floatx4 acc0 = {0,0,0,0}, acc1 = {0,0,0,0}, acc2 = {0,0,0,0}, acc3 = {0,0,0,0};
    floatx4 accd = {0,0,0,0};

    half8 bones;                     // B[k][0] = 1 -> col 0 of deg tile = row sums
#pragma unroll
    for (int e = 0; e < 8; ++e) bones[e] = (m == 0) ? (_Float16)1.0f : (_Float16)0.0f;

    floatx4 a_cur0, a_cur1, a_nxt0, a_nxt1;
    half8 v_cur0, v_cur1, v_cur2, v_cur3, v_nxt0, v_nxt1, v_nxt2, v_nxt3;

#define LOAD_A(t, x0, x1) do { int jj = (t) * 32 + 2 * jp; x0 = Abase[jj]; x1 = Abase[jj + 1]; } while (0)
#define LOAD_U(t, v0, v1, v2, v3) do { int jj = (t) * 32 + q * 8;                                  \
        v0 = *(const half8*)(Urow + (size_t)(0  + m) * N_ + jj);                                   \
        v1 = *(const half8*)(Urow + (size_t)(16 + m) * N_ + jj);                                   \
        v2 = *(const half8*)(Urow + (size_t)(32 + m) * N_ + jj);                                   \
        v3 = *(const half8*)(Urow + (size_t)(48 + m) * N_ + jj); } while (0)

    LOAD_A(0, a_cur0, a_cur1);
    LOAD_U(0, v_cur0, v_cur1, v_cur2, v_cur3);
    LOAD_A(1, a_nxt0, a_nxt1);
    LOAD_U(1, v_nxt0, v_nxt1, v_nxt2, v_nxt3);

#pragma unroll 2
    for (int t = 0; t < TSTEPS; ++t) {
        const int buf = t & 1;
        _Float16* dst = lds + buf * (4 * 16 * PJ);
        {   // fp32 -> fp16 (RNE) + LDS write: lane holds A[i_s][2jp..2jp+1][l=0..3]
            const float* c0 = (const float*)&a_cur0;
            const float* c1 = (const float*)&a_cur1;
#pragma unroll
            for (int l = 0; l < 4; ++l) {
                half2 h = {(_Float16)c0[l], (_Float16)c1[l]};
                *(half2*)(dst + (l * 16 + i_s) * PJ + 2 * jp) = h;
            }
        }
        // lgkmcnt-only barrier: do NOT drain vmcnt (keeps A/U prefetch in flight)
        __builtin_amdgcn_sched_barrier(0);
        asm volatile("s_waitcnt lgkmcnt(0)" ::: "memory");
        __builtin_amdgcn_s_barrier();
        __builtin_amdgcn_sched_barrier(0);

        // rotate prefetch (depth 2)
        a_cur0 = a_nxt0; a_cur1 = a_nxt1;
        const int tn = (t + 2 < TSTEPS) ? (t + 2) : (TSTEPS - 1);
        LOAD_A(tn, a_nxt0, a_nxt1);

        // compute: A-frag from LDS plane l=w, B-frags (U3 cols) from registers
        half8 af = *(const half8*)(lds + buf * (4 * 16 * PJ) + (w * 16 + m) * PJ + q * 8);
        acc0 = __builtin_amdgcn_mfma_f32_16x16x32_f16(af, v_cur0, acc0, 0, 0, 0);
        acc1 = __builtin_amdgcn_mfma_f32_16x16x32_f16(af, v_cur1, acc1, 0, 0, 0);
        acc2 = __builtin_amdgcn_mfma_f32_16x16x32_f16(af, v_cur2, acc2, 0, 0, 0);
        acc3 = __builtin_amdgcn_mfma_f32_16x16x32_f16(af, v_cur3, acc3, 0, 0, 0);
        accd = __builtin_amdgcn_mfma_f32_16x16x32_f16(af, bones,  accd, 0, 0, 0);

        v_cur0 = v_nxt0; v_cur1 = v_nxt1; v_cur2 = v_nxt2; v_cur3 = v_nxt3;
        LOAD_U(tn, v_nxt0, v_nxt1, v_nxt2, v_nxt3);
    }
#undef LOAD_A
#undef LOAD_U

    // ---- epilogue: wave w holds term3-partial for l=w: C[i=q*4+r][c-tile+m]
    {
        const float* f0 = (const float*)&acc0;
        const float* f1 = (const float*)&acc1;
        const float* f2 = (const float*)&acc2;
        const float* f3 = (const float*)&acc3;
#pragma unroll
        for (int r = 0; r < 4; ++r) {
            red[w][q * 4 + r][ 0 + m] = f0[r];
            red[w][q * 4 + r][16 + m] = f1[r];
            red[w][q * 4 + r][32 + m] = f2[r];
            red[w][q * 4 + r][48 + m] = f3[r];
        }
    }
    if (m == 0) {   // deg partial: accd col 0 = sum_j A[i,j,l=w]
        const int ibase = i0 + q * 4;
        *(floatx4*)(degT + ((size_t)((p * B_ + b) * L_ + w)) * N_ + ibase) = accd;
    }
    __syncthreads();

    // sum over l, write partial[p][b][i0/16][i][c]  (4 KB coalesced)
    {
        const int c = tid & 63;
        float* Pb = Ppart + (((size_t)(p * B_ + b) * (N_ / 16) + (i0 >> 4)) * 16) * 64;
#pragma unroll
        for (int r = 0; r < 4; ++r) {
            const int i = (tid >> 6) * 4 + r;
            Pb[i * 64 + c] = red[0][i][c] + red[1][i][c] + red[2][i][c] + red[3][i][c];
        }
    }
}

// ---------------------------------------------------------------------------
// K2: pure epilogue.  out = sigmoid(T1 + sum_l dsum*U2 - sum_p Ppart).
// grid = B * N/16 = 256 blocks, 256 thr.  ~9 MB read, ~2 us.
// ---------------------------------------------------------------------------
__global__ __launch_bounds__(256) void k2_fin(const float* __restrict__ Ppart,
                                              const float* __restrict__ degT,
                                              const float* __restrict__ U2,
                                              const float* __restrict__ T1,
                                              float* __restrict__ out) {
    __shared__ float dsum[4][16];
    const int b  = blockIdx.x >> 7;
    const int i0 = (blockIdx.x & 127) * 16;
    const int tid = threadIdx.x;

    if (tid < 64) {
        const int l = tid >> 4, i = tid & 15;
        float s = 0.0f;
#pragma unroll
        for (int p = 0; p < SK; ++p)
            s += degT[((size_t)((p * B_ + b) * L_ + l)) * N_ + i0 + i];
        dsum[l][i] = s;
    }
    __syncthreads();

    const int g = tid >> 6, c = tid & 63;
    const size_t PS = (size_t)B_ * (N_ / 16) * 16 * 64;   // per-p stride (1 MB / 4 B)
    const float* Pb = Ppart + (((size_t)b * (N_ / 16) + (i0 >> 4)) * 16) * 64;

#pragma unroll
    for (int r = 0; r < 4; ++r) {
        const int i = g * 4 + r;
        const size_t row = (size_t)(b * N_ + i0 + i);
        float acc = T1[row * 64 + c];
        acc += dsum[0][i] * U2[(row * 4 + 0) * 64 + c];
        acc += dsum[1][i] * U2[(row * 4 + 1) * 64 + c];
        acc += dsum[2][i] * U2[(row * 4 + 2) * 64 + c];
        acc += dsum[3][i] * U2[(row * 4 + 3) * 64 + c];
        acc -= Pb[i * 64 + c] + Pb[PS + i * 64 + c] + Pb[2 * PS + i * 64 + c] + Pb[3 * PS + i * 64 + c];
        out[row * 64 + c] = 1.0f / (1.0f + __expf(-acc));
    }
}

// ---------------------------------------------------------------------------
extern "C" void kernel_launch(void* const* d_in, const int* in_sizes, int n_in,
                              void* d_out, int out_size, void* d_ws, size_t ws_size,
                              hipStream_t stream) {
    const float* V  = (const float*)d_in[0];
    const float* A  = (const float*)d_in[1];
    const float* w1 = (const float*)d_in[2];
    const float* w2 = (const float*)d_in[3];
    const float* w3 = (const float*)d_in[4];
    float* out = (float*)d_out;

    char* ws = (char*)d_ws;
    float*    Ppart = (float*)(ws);                         // SK*B*N*C*4      = 4 MB
    float*    degT  = (float*)(ws + (4u << 20));            // SK*B*L*N*4      = 256 KB
    _Float16* U3    = (_Float16*)(ws + (4u << 20) + (256u << 10));   // B*L*C*N*2 = 2 MB
    float*    U2    = (float*)(ws + (6u << 20) + (256u << 10));      // B*N*L*C*4 = 4 MB
    float*    T1    = (float*)(ws + (10u << 20) + (256u << 10));     // B*N*C*4   = 1 MB

    hipLaunchKernelGGL(k0_embed, dim3(B_ * (N_ / 16)), dim3(256), 0, stream,
                       V, w1, w2, w3, U3, U2, T1);
    hipLaunchKernelGGL(k1_agg,   dim3(B_ * (N_ / 16) * SK), dim3(256), 0, stream,
                       A, U3, Ppart, degT);
    hipLaunchKernelGGL(k2_fin,   dim3(B_ * (N_ / 16)), dim3(256), 0, stream,
                       Ppart, degT, U2, T1, out);
}

// Round 5
// 218.309 us; speedup vs baseline: 1.1766x; 1.1766x over previous
//
#include <hip/hip_runtime.h>

// ROUND 5 = REVERT TO ROUND-2 VERIFIED KERNEL (217.1 us, absmax 3.9e-3).
// Round-4's algebraic restructure (fold w3 into V-side, l-reduce in K1)
// regressed to 256.9 us — post-mortem attributes it to K1 epilogue register
// pressure under launch_bounds(256,4) + latency-bound k0_embed at 1 block/CU.
// Decomposition model: ~190 us harness floor (2x512MiB poison fills @87% HBM
// + reset restores) + ~27 us kernels (k1 = 21 us, BW-bound on the 134 MB
// A-read; k0 2.5; k2 3).  Remaining controllable headroom ~3 us (<1.5%).

#define B_ 2
#define N_ 2048
#define F_ 64
#define C_ 64
#define L_ 4
#define SK 4    // split-K factor over j: 4 blocks/CU for latency decorrelation
#define NJ (N_ / SK)        // 512 j per block
#define TSTEPS (NJ / 32)    // 16 K-steps
#define PJ 40   // padded LDS j-stride (halves): 80 B rows -> 16B-aligned b128 reads, ~2-way banks

typedef _Float16 half8 __attribute__((ext_vector_type(8)));
typedef _Float16 half2 __attribute__((ext_vector_type(2)));
typedef float floatx4 __attribute__((ext_vector_type(4)));

// ---------------------------------------------------------------------------
// K0: V[b][j][f] -> Vth[b][f][j] (fp16), LDS transpose.
// grid = B * N/64 = 64 blocks, 256 threads
// ---------------------------------------------------------------------------
__global__ __launch_bounds__(256) void k0_transpose(const float* __restrict__ V,
                                                    _Float16* __restrict__ Vth) {
    __shared__ float tile[64][65];
    const int b  = blockIdx.x >> 5;          // 0..1
    const int j0 = (blockIdx.x & 31) * 64;   // j tile base
    const int tid = threadIdx.x;

    const floatx4* V4 = (const floatx4*)(V + ((size_t)(b * N_ + j0)) * F_);
#pragma unroll
    for (int s = 0; s < 4; ++s) {
        int g = tid + 256 * s;               // 0..1023 float4 slots
        int jl = g >> 4;                     // 0..63
        int fq = g & 15;                     // 0..15
        floatx4 v = V4[jl * 16 + fq];
        tile[jl][fq * 4 + 0] = v.x;
        tile[jl][fq * 4 + 1] = v.y;
        tile[jl][fq * 4 + 2] = v.z;
        tile[jl][fq * 4 + 3] = v.w;
    }
    __syncthreads();

    const int f = tid >> 2;                  // 0..63
    const int jb = (tid & 3) * 16;           // 0..48
    _Float16* dh = Vth + ((size_t)(b * F_ + f)) * N_ + j0 + jb;
#pragma unroll
    for (int u = 0; u < 16; u += 4) {
        half2 h01 = {(_Float16)tile[jb + u + 0][f], (_Float16)tile[jb + u + 1][f]};   // RNE
        half2 h23 = {(_Float16)tile[jb + u + 2][f], (_Float16)tile[jb + u + 3][f]};
        *(half2*)(dh + u + 0) = h01;
        *(half2*)(dh + u + 2) = h23;
    }
}

// ---------------------------------------------------------------------------
// K1: fused deg + agg via fp16 MFMA, split-K over j.  BW-bound at the 134 MB
// A-read floor (~21 us).  grid = B * N/16 * SK = 1024 blocks (4/CU), 256 thr.
// aggT layout [p][b][i>>2][k][i&3] so K2's partial-sum read is contiguous.
// ---------------------------------------------------------------------------
__global__ __launch_bounds__(256, 4) void k1_agg(const float* __restrict__ A,
                                                 const _Float16* __restrict__ Vth,
                                                 float* __restrict__ aggT,
                                                 float* __restrict__ degT) {
    __shared__ _Float16 lds[2 * 4 * 16 * PJ];   // 10 KB: [buf][l][i][PJ]

    const int bid = blockIdx.x;          // 0..1023
    const int b   = bid >> 9;
    const int rem = bid & 511;
    const int i0  = (rem >> 2) * 16;
    const int p   = rem & 3;             // split-K slice
    const int tid  = threadIdx.x;
    const int w    = tid >> 6;       // wave id == l
    const int lane = tid & 63;
    const int m    = lane & 15;      // A row / B col / C col within tile
    const int q    = lane >> 4;      // quad group

    // staging mapping: thread -> (row i_s, j-pair jp)
    const int i_s = tid >> 4;        // 0..15
    const int jp  = tid & 15;        // 0..15 -> j = 2jp, 2jp+1

    const floatx4* Abase = (const floatx4*)A + ((size_t)(b * N_ + i0 + i_s)) * N_ + p * NJ;
    const _Float16* Vrow = Vth + ((size_t)b * F_) * N_ + p * NJ;

    floatx4 acc0 = {0,0,0,0}, acc1 = {0,0,0,0}, acc2 = {0,0,0,0}, acc3 = {0,0,0,0};
    floatx4 accd = {0,0,0,0};

    half8 bones;                     // B[k][0] = 1 -> col 0 of deg tile = row sums
#pragma unroll
    for (int e = 0; e < 8; ++e) bones[e] = (m == 0) ? (_Float16)1.0f : (_Float16)0.0f;

    floatx4 a_cur0, a_cur1, a_nxt0, a_nxt1;
    half8 v_cur0, v_cur1, v_cur2, v_cur3, v_nxt0, v_nxt1, v_nxt2, v_nxt3;

#define LOAD_A(t, x0, x1) do { int jj = (t) * 32 + 2 * jp; x0 = Abase[jj]; x1 = Abase[jj + 1]; } while (0)
#define LOAD_V(t, v0, v1, v2, v3) do { int jj = (t) * 32 + q * 8;                                  \
        v0 = *(const half8*)(Vrow + (size_t)(0  + m) * N_ + jj);                                   \
        v1 = *(const half8*)(Vrow + (size_t)(16 + m) * N_ + jj);                                   \
        v2 = *(const half8*)(Vrow + (size_t)(32 + m) * N_ + jj);                                   \
        v3 = *(const half8*)(Vrow + (size_t)(48 + m) * N_ + jj); } while (0)

    LOAD_A(0, a_cur0, a_cur1);
    LOAD_V(0, v_cur0, v_cur1, v_cur2, v_cur3);
    LOAD_A(1, a_nxt0, a_nxt1);
    LOAD_V(1, v_nxt0, v_nxt1, v_nxt2, v_nxt3);

#pragma unroll 2
    for (int t = 0; t < TSTEPS; ++t) {
        const int buf = t & 1;
        _Float16* dst = lds + buf * (4 * 16 * PJ);
        {   // fp32 -> fp16 (RNE) + LDS write: lane holds A[i_s][2jp..2jp+1][l=0..3]
            const float* c0 = (const float*)&a_cur0;
            const float* c1 = (const float*)&a_cur1;
#pragma unroll
            for (int l = 0; l < 4; ++l) {
                half2 h = {(_Float16)c0[l], (_Float16)c1[l]};
                *(half2*)(dst + (l * 16 + i_s) * PJ + 2 * jp) = h;
            }
        }
        // lgkmcnt-only barrier: do NOT drain vmcnt (keeps A/V prefetch in flight)
        __builtin_amdgcn_sched_barrier(0);
        asm volatile("s_waitcnt lgkmcnt(0)" ::: "memory");
        __builtin_amdgcn_s_barrier();
        __builtin_amdgcn_sched_barrier(0);

        // rotate prefetch (depth 2: tile t+2 issued now, consumed at iter t+2)
        a_cur0 = a_nxt0; a_cur1 = a_nxt1;
        const int tn = (t + 2 < TSTEPS) ? (t + 2) : (TSTEPS - 1);
        LOAD_A(tn, a_nxt0, a_nxt1);

        // compute: A-frag from LDS plane l=w, B-frags from registers
        half8 af = *(const half8*)(lds + buf * (4 * 16 * PJ) + (w * 16 + m) * PJ + q * 8);
        acc0 = __builtin_amdgcn_mfma_f32_16x16x32_f16(af, v_cur0, acc0, 0, 0, 0);
        acc1 = __builtin_amdgcn_mfma_f32_16x16x32_f16(af, v_cur1, acc1, 0, 0, 0);
        acc2 = __builtin_amdgcn_mfma_f32_16x16x32_f16(af, v_cur2, acc2, 0, 0, 0);
        acc3 = __builtin_amdgcn_mfma_f32_16x16x32_f16(af, v_cur3, acc3, 0, 0, 0);
        accd = __builtin_amdgcn_mfma_f32_16x16x32_f16(af, bones,  accd, 0, 0, 0);

        v_cur0 = v_nxt0; v_cur1 = v_nxt1; v_cur2 = v_nxt2; v_cur3 = v_nxt3;
        LOAD_V(tn, v_nxt0, v_nxt1, v_nxt2, v_nxt3);
    }
#undef LOAD_A
#undef LOAD_V

    // epilogue: C layout col=lane&15 (f->k), row=q*4+reg (i).
    // aggT[p][b][it = i>>2][k][i&3]; 16 lanes (m) contiguous 256 B per store.
    float* aggb = aggT + ((size_t)(p * B_ + b)) * (512 * 1024);   // 2 MB per (p,b)
    float* rowp = aggb + ((size_t)((i0 >> 2) + q)) * 1024;
    *(floatx4*)(rowp + (w * 64 +  0 + m) * 4) = acc0;
    *(floatx4*)(rowp + (w * 64 + 16 + m) * 4) = acc1;
    *(floatx4*)(rowp + (w * 64 + 32 + m) * 4) = acc2;
    *(floatx4*)(rowp + (w * 64 + 48 + m) * 4) = acc3;
    if (m == 0) {
        const int ibase = i0 + q * 4;
        *(floatx4*)(degT + ((size_t)((p * B_ + b) * L_ + w)) * N_ + ibase) = accd;
    }
}

// ---------------------------------------------------------------------------
// K2: out[b,i,c] = sigmoid(V@w1 + (deg (x) V)@w2 - agg@w3), fp32 VALU.
// grid = B * N/4 = 1024 blocks, 256 thr.  Wave w owns f-quarter [16w,16w+16)
// and k-quarter [64w,64w+64), computes partials for all 4 i-rows (4x weight
// reuse), then 4 KB LDS cross-wave reduce.  ~3 us.
// ---------------------------------------------------------------------------
__global__ __launch_bounds__(256) void k2_out(const float* __restrict__ V,
                                              const float* __restrict__ degT,
                                              const float* __restrict__ aggT,
                                              const float* __restrict__ w1,
                                              const float* __restrict__ w2,
                                              const float* __restrict__ w3,
                                              float* __restrict__ out) {
    __shared__ float xsum[256][4];   // [k][i_loc]  summed agg partials
    __shared__ float vt[4][64];      // [i_loc][f]
    __shared__ float dsum[4][4];     // [l][i_loc]  summed deg partials
    __shared__ float red[4][4][64];  // [wave][i_loc][c] partial outputs

    const int raw = blockIdx.x;      // 0..1023
    const int b   = raw >> 9;
    const int t9  = raw & 511;
    // XCD swizzle: consecutive-i tiles land on the same XCD (bijection)
    const int tile = ((t9 & 7) << 6) | (t9 >> 3);
    const int i0  = tile * 4;
    const int tid = threadIdx.x;

    // phase 1a: xsum[k][0..3] = sum_p aggT[p][b][tile][k][0..3]  (contiguous)
    {
        const int k = tid;
        const float* g = aggT + (size_t)b * (512 * 1024) + (size_t)tile * 1024 + (size_t)k * 4;
        const size_t PS = (size_t)B_ * 512 * 1024;
        floatx4 s = *(const floatx4*)(g);
        s += *(const floatx4*)(g + PS);
        s += *(const floatx4*)(g + 2 * PS);
        s += *(const floatx4*)(g + 3 * PS);
        *(floatx4*)&xsum[k][0] = s;
    }
    // phase 1b: vt[i_loc][f] (coalesced 1 KB)
    {
        const int il = tid >> 6, f = tid & 63;
        vt[il][f] = V[((size_t)(b * N_ + i0 + il)) * F_ + f];
    }
    // phase 1c: dsum[l][i_loc]
    if (tid < 16) {
        const int l = tid >> 2, il = tid & 3;
        float s = 0.0f;
#pragma unroll
        for (int p = 0; p < SK; ++p)
            s += degT[((size_t)((p * B_ + b) * L_ + l)) * N_ + i0 + il];
        dsum[l][il] = s;
    }
    __syncthreads();

    // phase 2: wave w -> f in [16w,16w+16), k in [64w,64w+64); lane = c.
    const int w = tid >> 6;
    const int c = tid & 63;

    // hoist deg into registers (LDS broadcast, static indices after unroll)
    float dl[4][4];
#pragma unroll
    for (int l = 0; l < 4; ++l)
#pragma unroll
        for (int il = 0; il < 4; ++il) dl[l][il] = dsum[l][il];

    float s0 = 0.0f, s1 = 0.0f, s2 = 0.0f, s3 = 0.0f;

    const int fbase = w * 16;
#pragma unroll 4
    for (int fi = 0; fi < 16; ++fi) {
        const int f = fbase + fi;
        const float W1  = w1[f * 64 + c];
        const float W20 = w2[(0 * 64 + f) * 64 + c];
        const float W21 = w2[(1 * 64 + f) * 64 + c];
        const float W22 = w2[(2 * 64 + f) * 64 + c];
        const float W23 = w2[(3 * 64 + f) * 64 + c];
        {
            float coef = W1 + dl[0][0] * W20 + dl[1][0] * W21 + dl[2][0] * W22 + dl[3][0] * W23;
            s0 += vt[0][f] * coef;
        }
        {
            float coef = W1 + dl[0][1] * W20 + dl[1][1] * W21 + dl[2][1] * W22 + dl[3][1] * W23;
            s1 += vt[1][f] * coef;
        }
        {
            float coef = W1 + dl[0][2] * W20 + dl[1][2] * W21 + dl[2][2] * W22 + dl[3][2] * W23;
            s2 += vt[2][f] * coef;
        }
        {
            float coef = W1 + dl[0][3] * W20 + dl[1][3] * W21 + dl[2][3] * W22 + dl[3][3] * W23;
            s3 += vt[3][f] * coef;
        }
    }

    const int kbase = w * 64;
#pragma unroll 4
    for (int ki = 0; ki < 64; ++ki) {
        const int k = kbase + ki;
        const float W3 = w3[k * 64 + c];
        const floatx4 xs = *(const floatx4*)&xsum[k][0];   // b128 broadcast
        s0 -= xs.x * W3;
        s1 -= xs.y * W3;
        s2 -= xs.z * W3;
        s3 -= xs.w * W3;
    }

    red[w][0][c] = s0;
    red[w][1][c] = s1;
    red[w][2][c] = s2;
    red[w][3][c] = s3;
    __syncthreads();

    // cross-wave reduce + sigmoid + store (wave = one i row, coalesced 256 B)
    {
        const int il = tid >> 6;
        const float acc = red[0][il][c] + red[1][il][c] + red[2][il][c] + red[3][il][c];
        out[((size_t)(b * N_ + i0 + il)) * C_ + c] = 1.0f / (1.0f + __expf(-acc));
    }
}

// ---------------------------------------------------------------------------
extern "C" void kernel_launch(void* const* d_in, const int* in_sizes, int n_in,
                              void* d_out, int out_size, void* d_ws, size_t ws_size,
                              hipStream_t stream) {
    const float* V  = (const float*)d_in[0];
    const float* A  = (const float*)d_in[1];
    const float* w1 = (const float*)d_in[2];
    const float* w2 = (const float*)d_in[3];
    const float* w3 = (const float*)d_in[4];
    float* out = (float*)d_out;

    char* ws = (char*)d_ws;
    float*    aggT = (float*)(ws);                  // SK*B*512*1024*4 = 16 MB (permuted layout)
    float*    degT = (float*)(ws + 16777216);       // SK*B*L*N*4   = 256 KB
    _Float16* Vth  = (_Float16*)(ws + 17039360);    // B*F*N*2      = 512 KB

    hipLaunchKernelGGL(k0_transpose, dim3(B_ * (N_ / 64)), dim3(256), 0, stream, V, Vth);
    hipLaunchKernelGGL(k1_agg,       dim3(B_ * (N_ / 16) * SK), dim3(256), 0, stream,
                       A, Vth, aggT, degT);
    hipLaunchKernelGGL(k2_out,       dim3(B_ * (N_ / 4)), dim3(256), 0, stream,
                       V, degT, aggT, w1, w2, w3, out);
}